// Round 7
// baseline (205.840 us; speedup 1.0000x reference)
//
#include <hip/hip_runtime.h>
#include <math.h>

#define T_IN 2048
#define TP   2051   // T+3 conv output length
#define F    256
#define H    384
#define NT2  129    // 16-t tiles in k2
#define NCS  258    // 8-t chunks (scan length) = 2*NT2
#define NC3  257    // k3 chunks of 8 covering TP
#define WTS  (256 * 384)

__device__ __forceinline__ float logsig(float z) {
    return (z >= 0.0f) ? -log1pf(__expf(-z)) : z - log1pf(__expf(z));
}

// ---------- PREP: conv1d -> xp | W transpose -> Wt[k][b] | q,o at t=2050 | zero zf/Gf ----------
__global__ __launch_bounds__(256) void prep(
    const float* __restrict__ x, const float* __restrict__ cw, const float* __restrict__ cb,
    const float* __restrict__ Wk, const float* __restrict__ Wi, const float* __restrict__ Wf,
    const float* __restrict__ Wq, const float* __restrict__ bq,
    const float* __restrict__ Wo, const float* __restrict__ bo,
    float* __restrict__ xp, float* __restrict__ Wt,
    float* __restrict__ qv, float* __restrict__ ov, float* __restrict__ zf) {
    int bx = blockIdx.x, tid = threadIdx.x;
    if (bx < 513) {                       // ---- conv: 4 t-rows per block
        int t = bx * 4 + (tid >> 6);
        int f4 = tid & 63;
        if (t >= TP) return;
        float w0 = cw[0], w1 = cw[1], w2 = cw[2], w3 = cw[3];
        float b = cb[0];
        float4 acc = {b, b, b, b};
        int i0 = t - 3;
        const float4* x4 = (const float4*)x;
        float wj[4] = {w0, w1, w2, w3};
        #pragma unroll
        for (int j = 0; j < 4; ++j) {
            int tt = i0 + j;
            if (tt >= 0 && tt < T_IN) {
                float4 xv = x4[tt * 64 + f4];
                acc.x = fmaf(wj[j], xv.x, acc.x);
                acc.y = fmaf(wj[j], xv.y, acc.y);
                acc.z = fmaf(wj[j], xv.z, acc.z);
                acc.w = fmaf(wj[j], xv.w, acc.w);
            }
        }
        ((float4*)xp)[t * 64 + f4] = acc;
    } else if (bx < 801) {                // ---- transpose W[b][k] -> Wt[j][k][b], 32x32 tiles
        __shared__ float tl[32][33];
        int tb = bx - 513;
        int j = tb / 96, rem = tb % 96;
        int k0 = (rem / 12) * 32, b0 = (rem % 12) * 32;
        const float* W = (j == 0) ? Wk : (j == 1) ? Wi : Wf;
        int c = tid & 31, r0 = tid >> 5;
        #pragma unroll
        for (int s = 0; s < 4; ++s) {
            int r = r0 + 8 * s;
            tl[r][c] = W[(b0 + r) * 256 + k0 + c];
        }
        __syncthreads();
        float* dst = Wt + j * WTS;
        #pragma unroll
        for (int s = 0; s < 4; ++s) {
            int rr = r0 + 8 * s;
            dst[(k0 + rr) * 384 + b0 + c] = tl[c][rr];
        }
    } else if (bx < 897) {                // ---- q/o at final timestep (conv row computed inline)
        int lane = tid & 63;
        int row = (bx - 801) * 4 + (tid >> 6);
        float b = cb[0];
        float4 xv = {b, b, b, b};
        #pragma unroll
        for (int j = 0; j < 4; ++j) {
            int tt = (TP - 1) - 3 + j;    // 2047..2050; only <T_IN contribute
            if (tt >= 0 && tt < T_IN) {
                float wj = cw[j];
                float4 xr = *(const float4*)&x[tt * 256 + lane * 4];
                xv.x = fmaf(wj, xr.x, xv.x);
                xv.y = fmaf(wj, xr.y, xv.y);
                xv.z = fmaf(wj, xr.z, xv.z);
                xv.w = fmaf(wj, xr.w, xv.w);
            }
        }
        float4 q4 = *(const float4*)&Wq[row * 256 + lane * 4];
        float4 o4 = *(const float4*)&Wo[row * 256 + lane * 4];
        float aq = fmaf(xv.x, q4.x, fmaf(xv.y, q4.y, fmaf(xv.z, q4.z, xv.w * q4.w)));
        float ao = fmaf(xv.x, o4.x, fmaf(xv.y, o4.y, fmaf(xv.z, o4.z, xv.w * o4.w)));
        #pragma unroll
        for (int off = 32; off; off >>= 1) {
            aq += __shfl_down(aq, off, 64);
            ao += __shfl_down(ao, off, 64);
        }
        if (lane == 0) {
            qv[row] = aq + bq[row];
            ov[row] = 1.0f / (1.0f + __expf(-(ao + bo[row])));
        }
    } else {                              // ---- zero atomics accumulator (zf[256] + Gf)
        zf[tid] = 0.0f;
        if (tid == 0) zf[256] = 0.0f;
    }
}

// ---------- K2: tile 16t x 64b x 3 mats. A from LDS (staged once), B from global/L2 ----------
// grid (129,6)=774 blocks, 256 thr: tx=tid&15 -> 4 b-cols, ty=tid>>4 -> 1 t-row.
// Per 4 k's: 1 LDS b128 + 12 VMEM b128 + 48 FMA -> VALU-bound (pipes split).
__global__ __launch_bounds__(256) void k2_proj(
    const float* __restrict__ xp, const float* __restrict__ Wt,
    const float* __restrict__ bk, const float* __restrict__ bi, const float* __restrict__ bf,
    float* __restrict__ zk, float* __restrict__ ai, float* __restrict__ lf,
    float* __restrict__ cs) {
    __shared__ float xl[16][260];     // [t][k], stride 260 (2-way max)
    __shared__ float csred[16][68];
    int tid = threadIdx.x;
    int t0 = blockIdx.x * 16, b0 = blockIdx.y * 64;
    int tx = tid & 15, ty = tid >> 4;
    // stage xp tile (once)
    #pragma unroll
    for (int q = 0; q < 4; ++q) {
        int flat = (tid + 256 * q) * 4;
        int r = flat >> 8, k = flat & 255;
        float4 v = {0.f, 0.f, 0.f, 0.f};
        if (t0 + r < TP) v = *(const float4*)&xp[(t0 + r) * 256 + k];
        *(float4*)&xl[r][k] = v;
    }
    __syncthreads();
    int c0 = b0 + 4 * tx;
    const float* pk = Wt + 0 * WTS + c0;
    const float* pi = Wt + 1 * WTS + c0;
    const float* pf = Wt + 2 * WTS + c0;
    float4 a0 = {0.f, 0.f, 0.f, 0.f}, a1 = a0, a2 = a0;
    #pragma unroll 2
    for (int k4 = 0; k4 < 256; k4 += 4) {
        float4 av = *(const float4*)&xl[ty][k4];
        float acar[4] = {av.x, av.y, av.z, av.w};
        #pragma unroll
        for (int u = 0; u < 4; ++u) {
            int kk = k4 + u;
            float a = acar[u];
            float4 bkv = *(const float4*)&pk[kk * 384];
            float4 biv = *(const float4*)&pi[kk * 384];
            float4 bfv = *(const float4*)&pf[kk * 384];
            a0.x = fmaf(a, bkv.x, a0.x); a0.y = fmaf(a, bkv.y, a0.y);
            a0.z = fmaf(a, bkv.z, a0.z); a0.w = fmaf(a, bkv.w, a0.w);
            a1.x = fmaf(a, biv.x, a1.x); a1.y = fmaf(a, biv.y, a1.y);
            a1.z = fmaf(a, biv.z, a1.z); a1.w = fmaf(a, biv.w, a1.w);
            a2.x = fmaf(a, bfv.x, a2.x); a2.y = fmaf(a, bfv.y, a2.y);
            a2.z = fmaf(a, bfv.z, a2.z); a2.w = fmaf(a, bfv.w, a2.w);
        }
    }
    // epilogue
    int t = t0 + ty;
    float4 l4 = {0.f, 0.f, 0.f, 0.f};
    if (t < TP) {
        float4 bk4 = *(const float4*)&bk[c0];
        float4 bi4 = *(const float4*)&bi[c0];
        float4 bf4 = *(const float4*)&bf[c0];
        const float sc = 0.05103103630798287f;  // 1/sqrt(384)
        int row = t * H + c0;
        float4 v;
        v.x = (a0.x + bk4.x) * sc; v.y = (a0.y + bk4.y) * sc;
        v.z = (a0.z + bk4.z) * sc; v.w = (a0.w + bk4.w) * sc;
        *(float4*)&zk[row] = v;
        v.x = a1.x + bi4.x; v.y = a1.y + bi4.y;
        v.z = a1.z + bi4.z; v.w = a1.w + bi4.w;
        *(float4*)&ai[row] = v;
        l4.x = logsig(a2.x + bf4.x); l4.y = logsig(a2.y + bf4.y);
        l4.z = logsig(a2.z + bf4.z); l4.w = logsig(a2.w + bf4.w);
        *(float4*)&lf[row] = l4;
    }
    *(float4*)&csred[ty][4 * tx] = l4;
    __syncthreads();
    if (tid < 128) {      // 8-t chunk sums -> cs[2*bx + half]
        int half = tid >> 6, col = tid & 63;
        float s = 0.f;
        #pragma unroll
        for (int r = 0; r < 8; ++r) s += csred[half * 8 + r][col];
        cs[(2 * blockIdx.x + half) * H + b0 + col] = s;
    }
}

// ---------- K3b: reverse exclusive scan over 258 chunk sums, grid 6x64 ----------
__global__ __launch_bounds__(64) void k3b_scan(const float* __restrict__ cs,
                                               float* __restrict__ co) {
    int b = blockIdx.x * 64 + threadIdx.x;
    float L = 0.0f;
    #pragma unroll 16
    for (int c = NCS - 1; c >= 0; --c) {
        co[c * H + b] = L;
        L += cs[c * H + b];
    }
}

// ---------- K3: fused w -> g -> atomic (z, G). grid NC3 x 384, chunk 8 t ----------
__global__ __launch_bounds__(384) void k3_fused(
    const float* __restrict__ ai, const float* __restrict__ lf,
    const float* __restrict__ zk, const float* __restrict__ co,
    const float* __restrict__ q, const float* __restrict__ xp,
    float* __restrict__ zf, float* __restrict__ Gf) {
    __shared__ float zred[6][256];
    __shared__ float gred[6];
    int tid = threadIdx.x;
    int w = tid >> 6, lane = tid & 63;
    int c = blockIdx.x, ts = c * 8;
    float co0 = co[c * H + tid];
    float qb = q[tid];
    float aiv[8], lfv[8], zkv[8];
    float4 xv[8];
    if (ts + 8 <= TP) {
        #pragma unroll
        for (int u = 0; u < 8; ++u) {
            int idx = (ts + u) * H + tid;
            aiv[u] = ai[idx]; lfv[u] = lf[idx]; zkv[u] = zk[idx];
            xv[u] = *(const float4*)&xp[(ts + u) * 256 + lane * 4];
        }
    } else {
        #pragma unroll
        for (int u = 0; u < 8; ++u) {
            if (ts + u < TP) {
                int idx = (ts + u) * H + tid;
                aiv[u] = ai[idx]; lfv[u] = lf[idx]; zkv[u] = zk[idx];
                xv[u] = *(const float4*)&xp[(ts + u) * 256 + lane * 4];
            } else {
                aiv[u] = -1e30f; lfv[u] = 0.f; zkv[u] = 0.f;
                xv[u].x = xv[u].y = xv[u].z = xv[u].w = 0.f;
            }
        }
    }
    float S = 0.f, gsum = 0.f;
    float z0 = 0.f, z1 = 0.f, z2 = 0.f, z3 = 0.f;
    #pragma unroll
    for (int u = 7; u >= 0; --u) {
        float wv = __expf(aiv[u] + co0 + S) * zkv[u] * qb;
        S += lfv[u];
        float s = wv;
        s += __shfl_xor(s, 1, 64);
        s += __shfl_xor(s, 2, 64);
        s += __shfl_xor(s, 4, 64);
        s += __shfl_xor(s, 8, 64);
        s += __shfl_xor(s, 16, 64);
        s += __shfl_xor(s, 32, 64);
        gsum += s;
        z0 = fmaf(s, xv[u].x, z0);
        z1 = fmaf(s, xv[u].y, z1);
        z2 = fmaf(s, xv[u].z, z2);
        z3 = fmaf(s, xv[u].w, z3);
    }
    zred[w][lane * 4 + 0] = z0;
    zred[w][lane * 4 + 1] = z1;
    zred[w][lane * 4 + 2] = z2;
    zred[w][lane * 4 + 3] = z3;
    if (lane == 0) gred[w] = gsum;
    __syncthreads();
    if (tid < 256) {
        float s = zred[0][tid] + zred[1][tid] + zred[2][tid]
                + zred[3][tid] + zred[4][tid] + zred[5][tid];
        atomicAdd(&zf[tid], s);
    }
    if (tid == 0)
        atomicAdd(Gf, gred[0] + gred[1] + gred[2] + gred[3] + gred[4] + gred[5]);
}

// ---------- K6: wave-per-row GEMV finalize, grid 96 ----------
__global__ __launch_bounds__(256) void k6_out(const float* __restrict__ zf,
        const float* __restrict__ Gf,
        const float* __restrict__ Wv, const float* __restrict__ bv,
        const float* __restrict__ o, float* __restrict__ out) {
    int tid = threadIdx.x;
    int lane = tid & 63;
    int row = blockIdx.x * 4 + (tid >> 6);
    float Gv = Gf[0];
    float4 zv = *(const float4*)&zf[lane * 4];
    float4 wv = *(const float4*)&Wv[row * 256 + lane * 4];
    float acc = fmaf(zv.x, wv.x, fmaf(zv.y, wv.y, fmaf(zv.z, wv.z, zv.w * wv.w)));
    #pragma unroll
    for (int off = 32; off; off >>= 1) acc += __shfl_down(acc, off, 64);
    if (lane == 0)
        out[row] = o[row] * (acc + bv[row] * Gv) / fmaxf(fabsf(Gv), 1.0f);
}

extern "C" void kernel_launch(void* const* d_in, const int* in_sizes, int n_in,
                              void* d_out, int out_size, void* d_ws, size_t ws_size,
                              hipStream_t stream) {
    const float* x  = (const float*)d_in[0];
    const float* Wq = (const float*)d_in[1];  const float* bq = (const float*)d_in[2];
    const float* Wk = (const float*)d_in[3];  const float* bk = (const float*)d_in[4];
    const float* Wv = (const float*)d_in[5];  const float* bv = (const float*)d_in[6];
    const float* Wi = (const float*)d_in[7];  const float* bi = (const float*)d_in[8];
    const float* Wf = (const float*)d_in[9];  const float* bf = (const float*)d_in[10];
    const float* Wo = (const float*)d_in[11]; const float* bo = (const float*)d_in[12];
    const float* cw = (const float*)d_in[13]; const float* cb = (const float*)d_in[14];
    float* out = (float*)d_out;

    float* ws = (float*)d_ws;
    float* xp  = ws;                       // TP*F   = 525056
    float* Wt  = xp  + TP * F;             // 3*256*384 = 294912
    float* zk  = Wt  + 3 * WTS;            // TP*H   = 787584
    float* ai  = zk  + TP * H;             // TP*H
    float* lf  = ai  + TP * H;             // TP*H
    float* cs  = lf  + TP * H;             // NCS*H  = 99072
    float* co  = cs  + NCS * H;            // NCS*H
    float* qv  = co  + NCS * H;            // H
    float* ov  = qv  + H;                  // H
    float* zf  = ov  + H;                  // F + 1 (zf[256] = Gf)
    float* Gf  = zf  + F;

    prep<<<898, 256, 0, stream>>>(x, cw, cb, Wk, Wi, Wf, Wq, bq, Wo, bo,
                                  xp, Wt, qv, ov, zf);
    k2_proj<<<dim3(NT2, 6), 256, 0, stream>>>(xp, Wt, bk, bi, bf, zk, ai, lf, cs);
    k3b_scan<<<6, 64, 0, stream>>>(cs, co);
    k3_fused<<<NC3, 384, 0, stream>>>(ai, lf, zk, co, qv, xp, zf, Gf);
    k6_out<<<96, 256, 0, stream>>>(zf, Gf, Wv, bv, ov, out);
}